// Round 21
// baseline (969.036 us; speedup 1.0000x reference)
//
#include <hip/hip_runtime.h>
#include <hip/hip_bf16.h>
#include <math.h>

typedef __hip_bfloat16 bf16;
typedef unsigned short u16;
typedef __attribute__((ext_vector_type(8))) short s8b;    // 8 bf16 MFMA frag
typedef __attribute__((ext_vector_type(4))) short s4h;    // 4 bf16 (8B)
typedef __attribute__((ext_vector_type(4))) float f32x4;  // MFMA C/D frag

#define B_N    16
#define E_N    25
#define T_N    300
#define C_N    3
#define D_N    64
#define H_N    8
#define HD_N   8
#define FF_N   256
#define L_N    4
#define NC_N   60
#define N_SEQ  400          // B*E
#define S_LEN  301          // T+1
#define NS_TOT 120400       // N_SEQ*S_LEN
#define NTILES 7525         // NS_TOT/16
#define EPS_F  1e-5f
#define N_IN   24
#define CONV_TOT 568576

#define MFMA16(a, b, c) __builtin_amdgcn_mfma_f32_16x16x32_bf16(a, b, c, 0, 0, 0)

struct ConvArgs { const void* src[N_IN]; };

__device__ __forceinline__ float waveSum(float v) {
#pragma unroll
    for (int off = 32; off > 0; off >>= 1) v += __shfl_xor(v, off, 64);
    return v;
}

__device__ __forceinline__ float gelu_exact(float x) {
    return 0.5f * x * (1.0f + erff(x * 0.70710678118654752f));
}

__device__ __forceinline__ u16 f2b(float x) {
    union { bf16 b; u16 s; } u;
    u.b = __float2bfloat16(x);
    return u.s;
}

// TRUNCATING convert (hot paths): 1 VALU op; bias <=1 ULP toward zero on
// paths proven tolerant (r13-r19: absmax frozen through 7 quantizations).
__device__ __forceinline__ u16 f2b_t(float x) {
    return (u16)(__float_as_uint(x) >> 16);
}

__device__ __forceinline__ void split1(float x, short* hi, short* lo) {
    union { bf16 b; short s; } uh, ul;
    uh.b = __float2bfloat16(x);
    ul.b = __float2bfloat16(x - __bfloat162float(uh.b));
    *hi = uh.s; *lo = ul.s;
}

// ---------------------------------------------------------------------------
// Kernel 0: dtype-sniffing input conversion (round-2 evidence: fp32-stored).
// ---------------------------------------------------------------------------
__global__ void convert_kernel(ConvArgs args, float* __restrict__ dst) {
    const int sizes[N_IN] = {360000,192,64,64,64,64,49152,768,16384,256,256,256,
                             256,256,65536,1024,65536,256,64,64,4096,64,3840,60};
    const int offs[N_IN]  = {0,360000,360192,360256,360320,360384,360448,409600,
                             410368,426752,427008,427264,427520,427776,428032,
                             493568,494592,560128,560384,560448,560512,564608,
                             564672,568512};
    int t = blockIdx.x;
    int n = sizes[t];
    bool isbf = (((const unsigned short*)args.src[3])[0] == 0x3F80u);
    float* d = dst + offs[t];
    int start  = threadIdx.x + blockIdx.y * blockDim.x;
    int stride = blockDim.x * gridDim.y;
    if (isbf) {
        const unsigned short* s = (const unsigned short*)args.src[t];
        for (int i = start; i < n; i += stride)
            d[i] = __uint_as_float(((unsigned int)s[i]) << 16);
    } else {
        const float* s = (const float*)args.src[t];
        for (int i = start; i < n; i += stride)
            d[i] = s[i];
    }
}

__global__ void split_kernel(const float* __restrict__ src,
                             short* __restrict__ hi, short* __restrict__ lo,
                             int n) {
    int i = blockIdx.x * 256 + threadIdx.x;
    if (i < n) split1(src[i], &hi[i], &lo[i]);
}

// ---------------------------------------------------------------------------
// Kernel 1: embed + LayerNorm + cls prepend + positional encoding
// ---------------------------------------------------------------------------
__global__ void embed_kernel(const float* __restrict__ x,
                             const float* __restrict__ ew,
                             const float* __restrict__ ebias,
                             const float* __restrict__ g,
                             const float* __restrict__ bb,
                             const float* __restrict__ cls,
                             float* __restrict__ h) {
    int wave = threadIdx.x >> 6;
    int lane = threadIdx.x & 63;
    int row  = blockIdx.x * 4 + wave;
    if (row >= NS_TOT) return;
    int n = row / S_LEN;
    int s = row - n * S_LEN;
    int d = lane;

    float i2  = (float)(d & ~1);
    float div = expf(i2 * (-0.14391156515f));
    float ang = (float)s * div;
    float pe  = (d & 1) ? cosf(ang) : sinf(ang);

    float val;
    if (s == 0) {
        val = cls[d];
    } else {
        int t = s - 1;
        int bidx = n / E_N;
        int e    = n - bidx * E_N;
        int xb   = ((bidx * C_N + 0) * T_N + t) * E_N + e;
        float x0 = x[xb];
        float x1 = x[xb + T_N * E_N];
        float x2 = x[xb + 2 * T_N * E_N];
        float emb = x0 * ew[d * 3 + 0] + x1 * ew[d * 3 + 1]
                  + x2 * ew[d * 3 + 2] + ebias[d];
        float mu  = waveSum(emb) * (1.0f / 64.0f);
        float c   = emb - mu;
        float var = waveSum(c * c) * (1.0f / 64.0f);
        val = c * rsqrtf(var + EPS_F) * g[d] + bb[d];
    }
    h[row * 64 + d] = val + pe;
}

// ---------------------------------------------------------------------------
// Kernel 2: LN1 + QKV projection, PAIRED tiles, FULL BF16 operands
// (round-18/19, verified).
// ---------------------------------------------------------------------------
__global__ void __launch_bounds__(64)
ln_qkv_mfma(const float* __restrict__ h,
            const float* __restrict__ ln_g, const float* __restrict__ ln_b,
            const short* __restrict__ whi,  const float* __restrict__ wb,
            u16* __restrict__ qbuf, u16* __restrict__ kbuf,
            u16* __restrict__ vbuf) {
    __shared__ u16 Yu[2][16 * 72];
    int lane = threadIdx.x;
    int m = lane & 15, quad = lane >> 4;
    int tile0 = blockIdx.x * 2;
    int tile1 = (tile0 + 1 < NTILES) ? tile0 + 1 : tile0;
    bool wr1  = (tile0 + 1 < NTILES);
    int rb[2] = {tile0 * 16, tile1 * 16};

    float4 gv = ((const float4*)ln_g)[m], bv = ((const float4*)ln_b)[m];
    s8b A[2][2];

#pragma unroll
    for (int tt = 0; tt < 2; tt++) {
        const float4* h4 = (const float4*)(h + (size_t)rb[tt] * 64);
#pragma unroll
        for (int t = 0; t < 4; t++) {
            int r = t * 4 + quad;
            float4 v = h4[r * 16 + m];
            float s  = v.x + v.y + v.z + v.w;
            float ss = v.x*v.x + v.y*v.y + v.z*v.z + v.w*v.w;
#pragma unroll
            for (int off = 1; off < 16; off <<= 1) {
                s  += __shfl_xor(s,  off, 64);
                ss += __shfl_xor(ss, off, 64);
            }
            float mu = s * (1.0f / 64.0f);
            float rs = rsqrtf(ss * (1.0f / 64.0f) - mu * mu + EPS_F);
            s4h y;
            y[0] = (short)f2b_t((v.x - mu) * rs * gv.x + bv.x);
            y[1] = (short)f2b_t((v.y - mu) * rs * gv.y + bv.y);
            y[2] = (short)f2b_t((v.z - mu) * rs * gv.z + bv.z);
            y[3] = (short)f2b_t((v.w - mu) * rs * gv.w + bv.w);
            *(s4h*)&Yu[tt][r * 72 + m * 4] = y;
        }
#pragma unroll
        for (int kt = 0; kt < 2; kt++)
            A[tt][kt] = *(const s8b*)&Yu[tt][m * 72 + kt * 32 + quad * 8];
    }

    int nn[2][4], ssq[2][4];
#pragma unroll
    for (int tt = 0; tt < 2; tt++)
#pragma unroll
        for (int reg = 0; reg < 4; reg++) {
            int row = rb[tt] + quad * 4 + reg;
            nn[tt][reg]  = row / S_LEN;
            ssq[tt][reg] = row - nn[tt][reg] * S_LEN;
        }

    const float scale = 0.35355339059327373f;  // 1/sqrt(8), folded into q
    f32x4 zero = {0.f, 0.f, 0.f, 0.f};
#pragma unroll
    for (int nt = 0; nt < 12; nt++) {
        const short* p = whi + (nt * 16 + m) * 64 + quad * 8;
        s8b bh0 = *(const s8b*)p;
        s8b bh1 = *(const s8b*)(p + 32);
        float bias = wb[nt * 16 + m];
        u16* dst = (nt < 4) ? qbuf : (nt < 8) ? kbuf : vbuf;
        float mul = (nt < 4) ? scale : 1.0f;
        int o64  = (nt & 3) * 16 + m;
        int head = o64 >> 3, j = o64 & 7;
#pragma unroll
        for (int tt = 0; tt < 2; tt++) {
            f32x4 c = zero;
            c = MFMA16(A[tt][0], bh0, c);
            c = MFMA16(A[tt][1], bh1, c);
            if (tt == 1 && !wr1) continue;
#pragma unroll
            for (int reg = 0; reg < 4; reg++)
                dst[(((nn[tt][reg] * 8 + head) * S_LEN + ssq[tt][reg]) << 3) + j]
                    = f2b_t((c[reg] + bias) * mul);
        }
    }
}

// ---------------------------------------------------------------------------
// Kernel 3: MFMA attention (round-19 structure, single-z grid) + stride-36
// Pbuf (r20-verified: SQ_LDS_BANK_CONFLICT = 0 — quads own disjoint bank
// octets on writes; read start banks m*18 mod 32 all-distinct).  Q-split
// reverted (r20: halving compute per staging instance made the kernel
// staging-latency-bound, 81 -> 137 us).
// ---------------------------------------------------------------------------
__global__ void __launch_bounds__(256)
attn_mfma(u16* __restrict__ qb, const u16* __restrict__ kb,
          const u16* __restrict__ vb) {
    __shared__ u16 Khi[320 * 8];                  // K rows (kcol) x 8 d
    __shared__ u16 Vthi[9 * 330];                 // V^T rows d(0..7)+ones(8)
    __shared__ u16 Pbuf[4][16 * 36];              // per-wave P tile

    int head = blockIdx.x, n = blockIdx.y;
    int tid  = threadIdx.x;
    int wv   = tid >> 6, lane = tid & 63;
    int m    = lane & 15, quad = lane >> 4;
    size_t base = ((size_t)(n * 8 + head)) * S_LEN * 8;

    {
        s8b zero8 = {0,0,0,0,0,0,0,0};
        for (int i = tid; i < 320; i += 256) {
            s8b v = (i < 301) ? *(const s8b*)(kb + base + (size_t)i * 8) : zero8;
            *(s8b*)&Khi[i * 8] = v;
        }
    }
    for (int s = tid; s < 320; s += 256) {
        union { s8b v; u16 e[8]; } row;
        row.v = (s8b){0,0,0,0,0,0,0,0};
        u16 one = 0;
        if (s < 301) {
            row.v = *(const s8b*)(vb + base + (size_t)s * 8);
            one = 0x3F80u;
        }
#pragma unroll
        for (int d = 0; d < 8; d++) Vthi[d * 330 + s] = row.e[d];
        Vthi[8 * 330 + s] = one;
    }
    __syncthreads();

    u16* Pw = &Pbuf[wv][0];

    for (int qt = wv; qt < 19; qt += 4) {
        int qbase = qt * 16;
        s8b Aq = {0,0,0,0,0,0,0,0};
        if (quad == 0) {
            int qr = qbase + m; if (qr > 300) qr = 300;
            Aq = *(const s8b*)(qb + base + (size_t)qr * 8);
        }

        f32x4 oacc = {0.f, 0.f, 0.f, 0.f};
        for (int c = 0; c < 10; c++) {
#pragma unroll
            for (int hh = 0; hh < 2; hh++) {
                int kcol = (2 * c + hh) * 16 + m;
                s8b bh = *(const s8b*)&Khi[kcol * 8];
                f32x4 sc = {0.f, 0.f, 0.f, 0.f};
                sc = MFMA16(Aq, bh, sc);
#pragma unroll
                for (int r = 0; r < 4; r++)
                    Pw[(quad * 4 + r) * 36 + hh * 16 + m] = f2b_t(__expf(sc[r]));
            }
            // in-wave LDS write->read ordering (validated r7/8/10/12-20)
            s8b Ap = *(const s8b*)&Pw[m * 36 + quad * 8];
            int vrow = (m <= 8) ? m : 8;
            s8b bvh = *(const s8b*)&Vthi[vrow * 330 + c * 32 + quad * 8];
            oacc = MFMA16(Ap, bvh, oacc);
        }

#pragma unroll
        for (int r = 0; r < 4; r++) {
            float l = __shfl(oacc[r], (lane & 48) | 8, 64);
            int qr = qbase + quad * 4 + r;
            if (m < 8 && qr < 301)
                qb[base + (size_t)qr * 8 + m] = f2b_t(oacc[r] / l);
        }
    }
}

// ---------------------------------------------------------------------------
// Kernel 4: FUSED out-projection + residual + LN2 + FF (round-19, verified).
// ---------------------------------------------------------------------------
__global__ void __launch_bounds__(64)
out_ff_mfma(float* __restrict__ h, const u16* __restrict__ qbuf,
            const short* __restrict__ wohi, const float* __restrict__ wob,
            const float* __restrict__ g2,  const float* __restrict__ b2,
            const short* __restrict__ w1hi, const float* __restrict__ b1,
            const short* __restrict__ w2hi, const float* __restrict__ b2b) {
    __shared__ u16 oLs[2][16 * 72];   // O gather; REUSED for Y after frags
    __shared__ u16 Ts[2][16 * 40];

    int lane = threadIdx.x;
    int m = lane & 15, quad = lane >> 4;
    int tile0 = blockIdx.x * 2;
    int tile1 = (tile0 + 1 < NTILES) ? tile0 + 1 : tile0;
    bool wr1  = (tile0 + 1 < NTILES);
    int rb[2] = {tile0 * 16, tile1 * 16};

    s8b AO[2][2];
#pragma unroll
    for (int tt = 0; tt < 2; tt++) {
        for (int i = lane; i < 1024; i += 64) {
            int r = i >> 6, k = i & 63;
            int row = rb[tt] + r;
            int n = row / S_LEN, s = row - n * S_LEN;
            int head = k >> 3, j = k & 7;
            oLs[tt][r * 72 + k] = qbuf[(((n * 8 + head) * S_LEN + s) << 3) + j];
        }
#pragma unroll
        for (int kt = 0; kt < 2; kt++)
            AO[tt][kt] = *(const s8b*)&oLs[tt][m * 72 + kt * 32 + quad * 8];
    }

    f32x4 zero = {0.f, 0.f, 0.f, 0.f};
    float hnew[2][4][4];
#pragma unroll
    for (int nt = 0; nt < 4; nt++) {
        const short* p = wohi + (nt * 16 + m) * 64 + quad * 8;
        s8b bh0 = *(const s8b*)p;
        s8b bh1 = *(const s8b*)(p + 32);
        int col = nt * 16 + m;
        float bias = wob[col];
#pragma unroll
        for (int tt = 0; tt < 2; tt++) {
            f32x4 c = zero;
            c = MFMA16(AO[tt][0], bh0, c);
            c = MFMA16(AO[tt][1], bh1, c);
#pragma unroll
            for (int reg = 0; reg < 4; reg++) {
                int row = rb[tt] + quad * 4 + reg;
                hnew[tt][nt][reg] = h[(size_t)row * 64 + col] + c[reg] + bias;
            }
        }
    }

    s8b A1[2][2];
#pragma unroll
    for (int tt = 0; tt < 2; tt++) {
#pragma unroll
        for (int reg = 0; reg < 4; reg++) {
            float s  = hnew[tt][0][reg] + hnew[tt][1][reg]
                     + hnew[tt][2][reg] + hnew[tt][3][reg];
            float ss = hnew[tt][0][reg]*hnew[tt][0][reg]
                     + hnew[tt][1][reg]*hnew[tt][1][reg]
                     + hnew[tt][2][reg]*hnew[tt][2][reg]
                     + hnew[tt][3][reg]*hnew[tt][3][reg];
#pragma unroll
            for (int off = 1; off < 16; off <<= 1) {
                s  += __shfl_xor(s,  off, 64);
                ss += __shfl_xor(ss, off, 64);
            }
            float mu = s * (1.0f / 64.0f);
            float rs = rsqrtf(ss * (1.0f / 64.0f) - mu * mu + EPS_F);
#pragma unroll
            for (int nt = 0; nt < 4; nt++) {
                int col = nt * 16 + m;
                oLs[tt][(quad * 4 + reg) * 72 + col] =
                    f2b_t((hnew[tt][nt][reg] - mu) * rs * g2[col] + b2[col]);
            }
        }
#pragma unroll
        for (int kt = 0; kt < 2; kt++)
            A1[tt][kt] = *(const s8b*)&oLs[tt][m * 72 + kt * 32 + quad * 8];
    }

    f32x4 acc2[2][4] = {{zero, zero, zero, zero}, {zero, zero, zero, zero}};
    for (int kt2 = 0; kt2 < 8; kt2++) {
#pragma unroll
        for (int half = 0; half < 2; half++) {
            int nt = kt2 * 2 + half;
            const short* p = w1hi + (nt * 16 + m) * 64 + quad * 8;
            s8b bh0 = *(const s8b*)p;
            s8b bh1 = *(const s8b*)(p + 32);
            float bias = b1[nt * 16 + m];
#pragma unroll
            for (int tt = 0; tt < 2; tt++) {
                f32x4 c = zero;
                c = MFMA16(A1[tt][0], bh0, c);
                c = MFMA16(A1[tt][1], bh1, c);
#pragma unroll
                for (int reg = 0; reg < 4; reg++)
                    Ts[tt][(quad * 4 + reg) * 40 + half * 16 + m] =
                        f2b_t(gelu_exact(c[reg] + bias));
            }
        }

        s8b A2[2];
#pragma unroll
        for (int tt = 0; tt < 2; tt++)
            A2[tt] = *(const s8b*)&Ts[tt][m * 40 + quad * 8];
#pragma unroll
        for (int nt2 = 0; nt2 < 4; nt2++) {
            const short* p = w2hi + (nt2 * 16 + m) * 256 + kt2 * 32 + quad * 8;
            s8b bh = *(const s8b*)p;
#pragma unroll
            for (int tt = 0; tt < 2; tt++)
                acc2[tt][nt2] = MFMA16(A2[tt], bh, acc2[tt][nt2]);
        }
    }

#pragma unroll
    for (int tt = 0; tt < 2; tt++) {
        if (tt == 1 && !wr1) break;
#pragma unroll
        for (int nt2 = 0; nt2 < 4; nt2++) {
            int col = nt2 * 16 + m;
            float bias = b2b[col];
#pragma unroll
            for (int reg = 0; reg < 4; reg++) {
                int row = rb[tt] + quad * 4 + reg;
                h[(size_t)row * 64 + col] =
                    hnew[tt][nt2][reg] + acc2[tt][nt2][reg] + bias;
            }
        }
    }
}

// ---------------------------------------------------------------------------
// Kernel 6: head — cls pooling, LN, gelu MLP, classifier (fp32 output).
// ---------------------------------------------------------------------------
__global__ void head_kernel(const float* __restrict__ h,
                            const float* __restrict__ ng,
                            const float* __restrict__ nb,
                            const float* __restrict__ w1,
                            const float* __restrict__ b1,
                            const float* __restrict__ w2,
                            const float* __restrict__ b2,
                            float* __restrict__ out) {
    __shared__ float feat[64];
    __shared__ float g1[64];
    int b = blockIdx.x, d = threadIdx.x;

    float s = 0.f;
    for (int e = 0; e < E_N; e++)
        s += h[(size_t)((b * E_N + e) * S_LEN) * 64 + d];
    s *= (1.0f / 25.0f);

    float mu  = waveSum(s) * (1.0f / 64.0f);
    float c   = s - mu;
    float var = waveSum(c * c) * (1.0f / 64.0f);
    feat[d] = c * rsqrtf(var + EPS_F) * ng[d] + nb[d];
    __syncthreads();

    float a = b1[d];
    for (int k = 0; k < 64; k++) a += feat[k] * w1[d * 64 + k];
    g1[d] = gelu_exact(a);
    __syncthreads();

    if (d < NC_N) {
        float a2 = b2[d];
        for (int k = 0; k < 64; k++) a2 += g1[k] * w2[d * 64 + k];
        out[b * NC_N + d] = a2;
    }
}

// ---------------------------------------------------------------------------
extern "C" void kernel_launch(void* const* d_in, const int* in_sizes, int n_in,
                              void* d_out, int out_size, void* d_ws, size_t ws_size,
                              hipStream_t stream) {
    ConvArgs ca;
    for (int i = 0; i < N_IN; i++) ca.src[i] = d_in[i];

    float* F = (float*)d_ws;
    const int offs[N_IN] = {0,360000,360192,360256,360320,360384,360448,409600,
                            410368,426752,427008,427264,427520,427776,428032,
                            493568,494592,560128,560384,560448,560512,564608,
                            564672,568512};
    const float* x       = F + offs[0];
    const float* embed_w = F + offs[1];
    const float* embed_b = F + offs[2];
    const float* eln_g   = F + offs[3];
    const float* eln_b   = F + offs[4];
    const float* cls     = F + offs[5];
    const float* qkv_w   = F + offs[6];
    const float* qkv_b   = F + offs[7];
    const float* out_w   = F + offs[8];
    const float* out_b   = F + offs[9];
    const float* ln1_g   = F + offs[10];
    const float* ln1_b   = F + offs[11];
    const float* ln2_g   = F + offs[12];
    const float* ln2_b   = F + offs[13];
    const float* ff1_w   = F + offs[14];
    const float* ff1_b   = F + offs[15];
    const float* ff2_w   = F + offs[16];
    const float* ff2_b   = F + offs[17];
    const float* norm_g  = F + offs[18];
    const float* norm_b  = F + offs[19];
    const float* h1_w    = F + offs[20];
    const float* h1_b    = F + offs[21];
    const float* h2_w    = F + offs[22];
    const float* h2_b    = F + offs[23];

    float* h   = F + CONV_TOT;                        // [NS_TOT][64] fp32
    u16* qbuf = (u16*)(h + (size_t)NS_TOT * 64);      // [N][H][S][8] bf16
    u16* kbuf = qbuf + (size_t)NS_TOT * 64;
    u16* vbuf = kbuf + (size_t)NS_TOT * 64;
    short* qwhi = (short*)(vbuf + (size_t)NS_TOT * 64);  // 49152 each
    short* qwlo = qwhi + 49152;
    short* w1hi = qwlo + 49152;                          // 65536 each
    short* w1lo = w1hi + 65536;
    short* w2hi = w1lo + 65536;
    short* w2lo = w2hi + 65536;
    short* wohi = w2lo + 65536;                          // 16384 each
    short* wolo = wohi + 16384;

    convert_kernel<<<dim3(N_IN, 8), 256, 0, stream>>>(ca, F);
    split_kernel<<<192, 256, 0, stream>>>(qkv_w, qwhi, qwlo, 49152);
    split_kernel<<<256, 256, 0, stream>>>(ff1_w, w1hi, w1lo, 65536);
    split_kernel<<<256, 256, 0, stream>>>(ff2_w, w2hi, w2lo, 65536);
    split_kernel<<<64, 256, 0, stream>>>(out_w, wohi, wolo, 16384);

    embed_kernel<<<NS_TOT / 4, 256, 0, stream>>>(x, embed_w, embed_b,
                                                 eln_g, eln_b, cls, h);

    for (int l = 0; l < L_N; l++) {
        ln_qkv_mfma<<<(NTILES + 1) / 2, 64, 0, stream>>>(
            h, ln1_g + l * 64, ln1_b + l * 64,
            qwhi + l * 12288, qkv_b + l * 192,
            qbuf, kbuf, vbuf);
        attn_mfma<<<dim3(H_N, N_SEQ), 256, 0, stream>>>(qbuf, kbuf, vbuf);
        out_ff_mfma<<<(NTILES + 1) / 2, 64, 0, stream>>>(
            h, qbuf,
            wohi + l * 4096, out_b + l * 64,
            ln2_g + l * 64, ln2_b + l * 64,
            w1hi + l * 16384, ff1_b + l * 256,
            w2hi + l * 16384, ff2_b + l * 64);
    }

    head_kernel<<<B_N, 64, 0, stream>>>(h, norm_g, norm_b,
                                        h1_w, h1_b, h2_w, h2_b,
                                        (float*)d_out);
}

// Round 22
// 740.424 us; speedup vs baseline: 1.3088x; 1.3088x over previous
//
#include <hip/hip_runtime.h>
#include <hip/hip_bf16.h>
#include <math.h>

typedef __hip_bfloat16 bf16;
typedef unsigned short u16;
typedef __attribute__((ext_vector_type(8))) short s8b;    // 8 bf16 MFMA frag
typedef __attribute__((ext_vector_type(4))) short s4h;    // 4 bf16 (8B)
typedef __attribute__((ext_vector_type(4))) float f32x4;  // MFMA C/D frag

#define B_N    16
#define E_N    25
#define T_N    300
#define C_N    3
#define D_N    64
#define H_N    8
#define HD_N   8
#define FF_N   256
#define L_N    4
#define NC_N   60
#define N_SEQ  400          // B*E
#define S_LEN  301          // T+1
#define NS_TOT 120400       // N_SEQ*S_LEN
#define NTILES 7525         // NS_TOT/16
#define EPS_F  1e-5f
#define N_IN   24
#define CONV_TOT 568576

#define MFMA16(a, b, c) __builtin_amdgcn_mfma_f32_16x16x32_bf16(a, b, c, 0, 0, 0)

struct ConvArgs { const void* src[N_IN]; };

__device__ __forceinline__ float waveSum(float v) {
#pragma unroll
    for (int off = 32; off > 0; off >>= 1) v += __shfl_xor(v, off, 64);
    return v;
}

__device__ __forceinline__ float gelu_exact(float x) {
    return 0.5f * x * (1.0f + erff(x * 0.70710678118654752f));
}

__device__ __forceinline__ u16 f2b(float x) {
    union { bf16 b; u16 s; } u;
    u.b = __float2bfloat16(x);
    return u.s;
}

// TRUNCATING convert (hot paths): 1 VALU op; bias <=1 ULP toward zero on
// paths proven tolerant (r13-r19: absmax frozen through 7 quantizations).
__device__ __forceinline__ u16 f2b_t(float x) {
    return (u16)(__float_as_uint(x) >> 16);
}

__device__ __forceinline__ void split1(float x, short* hi, short* lo) {
    union { bf16 b; short s; } uh, ul;
    uh.b = __float2bfloat16(x);
    ul.b = __float2bfloat16(x - __bfloat162float(uh.b));
    *hi = uh.s; *lo = ul.s;
}

// ---------------------------------------------------------------------------
// Kernel 0: dtype-sniffing input conversion (round-2 evidence: fp32-stored).
// ---------------------------------------------------------------------------
__global__ void convert_kernel(ConvArgs args, float* __restrict__ dst) {
    const int sizes[N_IN] = {360000,192,64,64,64,64,49152,768,16384,256,256,256,
                             256,256,65536,1024,65536,256,64,64,4096,64,3840,60};
    const int offs[N_IN]  = {0,360000,360192,360256,360320,360384,360448,409600,
                             410368,426752,427008,427264,427520,427776,428032,
                             493568,494592,560128,560384,560448,560512,564608,
                             564672,568512};
    int t = blockIdx.x;
    int n = sizes[t];
    bool isbf = (((const unsigned short*)args.src[3])[0] == 0x3F80u);
    float* d = dst + offs[t];
    int start  = threadIdx.x + blockIdx.y * blockDim.x;
    int stride = blockDim.x * gridDim.y;
    if (isbf) {
        const unsigned short* s = (const unsigned short*)args.src[t];
        for (int i = start; i < n; i += stride)
            d[i] = __uint_as_float(((unsigned int)s[i]) << 16);
    } else {
        const float* s = (const float*)args.src[t];
        for (int i = start; i < n; i += stride)
            d[i] = s[i];
    }
}

__global__ void split_kernel(const float* __restrict__ src,
                             short* __restrict__ hi, short* __restrict__ lo,
                             int n) {
    int i = blockIdx.x * 256 + threadIdx.x;
    if (i < n) split1(src[i], &hi[i], &lo[i]);
}

// ---------------------------------------------------------------------------
// Kernel 1: embed + LayerNorm + cls prepend + positional encoding
// ---------------------------------------------------------------------------
__global__ void embed_kernel(const float* __restrict__ x,
                             const float* __restrict__ ew,
                             const float* __restrict__ ebias,
                             const float* __restrict__ g,
                             const float* __restrict__ bb,
                             const float* __restrict__ cls,
                             float* __restrict__ h) {
    int wave = threadIdx.x >> 6;
    int lane = threadIdx.x & 63;
    int row  = blockIdx.x * 4 + wave;
    if (row >= NS_TOT) return;
    int n = row / S_LEN;
    int s = row - n * S_LEN;
    int d = lane;

    float i2  = (float)(d & ~1);
    float div = expf(i2 * (-0.14391156515f));
    float ang = (float)s * div;
    float pe  = (d & 1) ? cosf(ang) : sinf(ang);

    float val;
    if (s == 0) {
        val = cls[d];
    } else {
        int t = s - 1;
        int bidx = n / E_N;
        int e    = n - bidx * E_N;
        int xb   = ((bidx * C_N + 0) * T_N + t) * E_N + e;
        float x0 = x[xb];
        float x1 = x[xb + T_N * E_N];
        float x2 = x[xb + 2 * T_N * E_N];
        float emb = x0 * ew[d * 3 + 0] + x1 * ew[d * 3 + 1]
                  + x2 * ew[d * 3 + 2] + ebias[d];
        float mu  = waveSum(emb) * (1.0f / 64.0f);
        float c   = emb - mu;
        float var = waveSum(c * c) * (1.0f / 64.0f);
        val = c * rsqrtf(var + EPS_F) * g[d] + bb[d];
    }
    h[row * 64 + d] = val + pe;
}

// ---------------------------------------------------------------------------
// Kernel 2: LN1 + QKV projection, PAIRED tiles, FULL BF16 operands
// (round-18/19, verified).
// ---------------------------------------------------------------------------
__global__ void __launch_bounds__(64)
ln_qkv_mfma(const float* __restrict__ h,
            const float* __restrict__ ln_g, const float* __restrict__ ln_b,
            const short* __restrict__ whi,  const float* __restrict__ wb,
            u16* __restrict__ qbuf, u16* __restrict__ kbuf,
            u16* __restrict__ vbuf) {
    __shared__ u16 Yu[2][16 * 72];
    int lane = threadIdx.x;
    int m = lane & 15, quad = lane >> 4;
    int tile0 = blockIdx.x * 2;
    int tile1 = (tile0 + 1 < NTILES) ? tile0 + 1 : tile0;
    bool wr1  = (tile0 + 1 < NTILES);
    int rb[2] = {tile0 * 16, tile1 * 16};

    float4 gv = ((const float4*)ln_g)[m], bv = ((const float4*)ln_b)[m];
    s8b A[2][2];

#pragma unroll
    for (int tt = 0; tt < 2; tt++) {
        const float4* h4 = (const float4*)(h + (size_t)rb[tt] * 64);
#pragma unroll
        for (int t = 0; t < 4; t++) {
            int r = t * 4 + quad;
            float4 v = h4[r * 16 + m];
            float s  = v.x + v.y + v.z + v.w;
            float ss = v.x*v.x + v.y*v.y + v.z*v.z + v.w*v.w;
#pragma unroll
            for (int off = 1; off < 16; off <<= 1) {
                s  += __shfl_xor(s,  off, 64);
                ss += __shfl_xor(ss, off, 64);
            }
            float mu = s * (1.0f / 64.0f);
            float rs = rsqrtf(ss * (1.0f / 64.0f) - mu * mu + EPS_F);
            s4h y;
            y[0] = (short)f2b_t((v.x - mu) * rs * gv.x + bv.x);
            y[1] = (short)f2b_t((v.y - mu) * rs * gv.y + bv.y);
            y[2] = (short)f2b_t((v.z - mu) * rs * gv.z + bv.z);
            y[3] = (short)f2b_t((v.w - mu) * rs * gv.w + bv.w);
            *(s4h*)&Yu[tt][r * 72 + m * 4] = y;
        }
#pragma unroll
        for (int kt = 0; kt < 2; kt++)
            A[tt][kt] = *(const s8b*)&Yu[tt][m * 72 + kt * 32 + quad * 8];
    }

    int nn[2][4], ssq[2][4];
#pragma unroll
    for (int tt = 0; tt < 2; tt++)
#pragma unroll
        for (int reg = 0; reg < 4; reg++) {
            int row = rb[tt] + quad * 4 + reg;
            nn[tt][reg]  = row / S_LEN;
            ssq[tt][reg] = row - nn[tt][reg] * S_LEN;
        }

    const float scale = 0.35355339059327373f;  // 1/sqrt(8), folded into q
    f32x4 zero = {0.f, 0.f, 0.f, 0.f};
#pragma unroll
    for (int nt = 0; nt < 12; nt++) {
        const short* p = whi + (nt * 16 + m) * 64 + quad * 8;
        s8b bh0 = *(const s8b*)p;
        s8b bh1 = *(const s8b*)(p + 32);
        float bias = wb[nt * 16 + m];
        u16* dst = (nt < 4) ? qbuf : (nt < 8) ? kbuf : vbuf;
        float mul = (nt < 4) ? scale : 1.0f;
        int o64  = (nt & 3) * 16 + m;
        int head = o64 >> 3, j = o64 & 7;
#pragma unroll
        for (int tt = 0; tt < 2; tt++) {
            f32x4 c = zero;
            c = MFMA16(A[tt][0], bh0, c);
            c = MFMA16(A[tt][1], bh1, c);
            if (tt == 1 && !wr1) continue;
#pragma unroll
            for (int reg = 0; reg < 4; reg++)
                dst[(((nn[tt][reg] * 8 + head) * S_LEN + ssq[tt][reg]) << 3) + j]
                    = f2b_t((c[reg] + bias) * mul);
        }
    }
}

// ---------------------------------------------------------------------------
// Kernel 3: MFMA attention — EXACT round-19 version (best measured: 81 us).
// Pbuf stride 40: 16B-ALIGNED b128 P-reads (stride-36 r20/r21 zeroed the
// conflicts but broke 16B alignment for odd m -> split reads on the serial
// chain, 81 -> 138 us; the 2.43M conflicts cost only ~5%).  Single-z grid
// (Q-split r20 made the kernel staging-latency-bound).
// ---------------------------------------------------------------------------
__global__ void __launch_bounds__(256)
attn_mfma(u16* __restrict__ qb, const u16* __restrict__ kb,
          const u16* __restrict__ vb) {
    __shared__ u16 Khi[320 * 8];                  // K rows (kcol) x 8 d
    __shared__ u16 Vthi[9 * 330];                 // V^T rows d(0..7)+ones(8)
    __shared__ u16 Pbuf[4][16 * 40];              // per-wave P tile

    int head = blockIdx.x, n = blockIdx.y;
    int tid  = threadIdx.x;
    int wv   = tid >> 6, lane = tid & 63;
    int m    = lane & 15, quad = lane >> 4;
    size_t base = ((size_t)(n * 8 + head)) * S_LEN * 8;

    {
        s8b zero8 = {0,0,0,0,0,0,0,0};
        for (int i = tid; i < 320; i += 256) {
            s8b v = (i < 301) ? *(const s8b*)(kb + base + (size_t)i * 8) : zero8;
            *(s8b*)&Khi[i * 8] = v;
        }
    }
    for (int s = tid; s < 320; s += 256) {
        union { s8b v; u16 e[8]; } row;
        row.v = (s8b){0,0,0,0,0,0,0,0};
        u16 one = 0;
        if (s < 301) {
            row.v = *(const s8b*)(vb + base + (size_t)s * 8);
            one = 0x3F80u;
        }
#pragma unroll
        for (int d = 0; d < 8; d++) Vthi[d * 330 + s] = row.e[d];
        Vthi[8 * 330 + s] = one;
    }
    __syncthreads();

    u16* Pw = &Pbuf[wv][0];

    for (int qt = wv; qt < 19; qt += 4) {
        int qbase = qt * 16;
        s8b Aq = {0,0,0,0,0,0,0,0};
        if (quad == 0) {
            int qr = qbase + m; if (qr > 300) qr = 300;
            Aq = *(const s8b*)(qb + base + (size_t)qr * 8);
        }

        f32x4 oacc = {0.f, 0.f, 0.f, 0.f};
        for (int c = 0; c < 10; c++) {
#pragma unroll
            for (int hh = 0; hh < 2; hh++) {
                int kcol = (2 * c + hh) * 16 + m;
                s8b bh = *(const s8b*)&Khi[kcol * 8];
                f32x4 sc = {0.f, 0.f, 0.f, 0.f};
                sc = MFMA16(Aq, bh, sc);
#pragma unroll
                for (int r = 0; r < 4; r++)
                    Pw[(quad * 4 + r) * 40 + hh * 16 + m] = f2b_t(__expf(sc[r]));
            }
            // in-wave LDS write->read ordering (validated r7/8/10/12-21)
            s8b Ap = *(const s8b*)&Pw[m * 40 + quad * 8];
            int vrow = (m <= 8) ? m : 8;
            s8b bvh = *(const s8b*)&Vthi[vrow * 330 + c * 32 + quad * 8];
            oacc = MFMA16(Ap, bvh, oacc);
        }

#pragma unroll
        for (int r = 0; r < 4; r++) {
            float l = __shfl(oacc[r], (lane & 48) | 8, 64);
            int qr = qbase + quad * 4 + r;
            if (m < 8 && qr < 301)
                qb[base + (size_t)qr * 8 + m] = f2b_t(oacc[r] / l);
        }
    }
}

// ---------------------------------------------------------------------------
// Kernel 4: FUSED out-projection + residual + LN2 + FF (round-19, verified).
// ---------------------------------------------------------------------------
__global__ void __launch_bounds__(64)
out_ff_mfma(float* __restrict__ h, const u16* __restrict__ qbuf,
            const short* __restrict__ wohi, const float* __restrict__ wob,
            const float* __restrict__ g2,  const float* __restrict__ b2,
            const short* __restrict__ w1hi, const float* __restrict__ b1,
            const short* __restrict__ w2hi, const float* __restrict__ b2b) {
    __shared__ u16 oLs[2][16 * 72];   // O gather; REUSED for Y after frags
    __shared__ u16 Ts[2][16 * 40];

    int lane = threadIdx.x;
    int m = lane & 15, quad = lane >> 4;
    int tile0 = blockIdx.x * 2;
    int tile1 = (tile0 + 1 < NTILES) ? tile0 + 1 : tile0;
    bool wr1  = (tile0 + 1 < NTILES);
    int rb[2] = {tile0 * 16, tile1 * 16};

    s8b AO[2][2];
#pragma unroll
    for (int tt = 0; tt < 2; tt++) {
        for (int i = lane; i < 1024; i += 64) {
            int r = i >> 6, k = i & 63;
            int row = rb[tt] + r;
            int n = row / S_LEN, s = row - n * S_LEN;
            int head = k >> 3, j = k & 7;
            oLs[tt][r * 72 + k] = qbuf[(((n * 8 + head) * S_LEN + s) << 3) + j];
        }
#pragma unroll
        for (int kt = 0; kt < 2; kt++)
            AO[tt][kt] = *(const s8b*)&oLs[tt][m * 72 + kt * 32 + quad * 8];
    }

    f32x4 zero = {0.f, 0.f, 0.f, 0.f};
    float hnew[2][4][4];
#pragma unroll
    for (int nt = 0; nt < 4; nt++) {
        const short* p = wohi + (nt * 16 + m) * 64 + quad * 8;
        s8b bh0 = *(const s8b*)p;
        s8b bh1 = *(const s8b*)(p + 32);
        int col = nt * 16 + m;
        float bias = wob[col];
#pragma unroll
        for (int tt = 0; tt < 2; tt++) {
            f32x4 c = zero;
            c = MFMA16(AO[tt][0], bh0, c);
            c = MFMA16(AO[tt][1], bh1, c);
#pragma unroll
            for (int reg = 0; reg < 4; reg++) {
                int row = rb[tt] + quad * 4 + reg;
                hnew[tt][nt][reg] = h[(size_t)row * 64 + col] + c[reg] + bias;
            }
        }
    }

    s8b A1[2][2];
#pragma unroll
    for (int tt = 0; tt < 2; tt++) {
#pragma unroll
        for (int reg = 0; reg < 4; reg++) {
            float s  = hnew[tt][0][reg] + hnew[tt][1][reg]
                     + hnew[tt][2][reg] + hnew[tt][3][reg];
            float ss = hnew[tt][0][reg]*hnew[tt][0][reg]
                     + hnew[tt][1][reg]*hnew[tt][1][reg]
                     + hnew[tt][2][reg]*hnew[tt][2][reg]
                     + hnew[tt][3][reg]*hnew[tt][3][reg];
#pragma unroll
            for (int off = 1; off < 16; off <<= 1) {
                s  += __shfl_xor(s,  off, 64);
                ss += __shfl_xor(ss, off, 64);
            }
            float mu = s * (1.0f / 64.0f);
            float rs = rsqrtf(ss * (1.0f / 64.0f) - mu * mu + EPS_F);
#pragma unroll
            for (int nt = 0; nt < 4; nt++) {
                int col = nt * 16 + m;
                oLs[tt][(quad * 4 + reg) * 72 + col] =
                    f2b_t((hnew[tt][nt][reg] - mu) * rs * g2[col] + b2[col]);
            }
        }
#pragma unroll
        for (int kt = 0; kt < 2; kt++)
            A1[tt][kt] = *(const s8b*)&oLs[tt][m * 72 + kt * 32 + quad * 8];
    }

    f32x4 acc2[2][4] = {{zero, zero, zero, zero}, {zero, zero, zero, zero}};
    for (int kt2 = 0; kt2 < 8; kt2++) {
#pragma unroll
        for (int half = 0; half < 2; half++) {
            int nt = kt2 * 2 + half;
            const short* p = w1hi + (nt * 16 + m) * 64 + quad * 8;
            s8b bh0 = *(const s8b*)p;
            s8b bh1 = *(const s8b*)(p + 32);
            float bias = b1[nt * 16 + m];
#pragma unroll
            for (int tt = 0; tt < 2; tt++) {
                f32x4 c = zero;
                c = MFMA16(A1[tt][0], bh0, c);
                c = MFMA16(A1[tt][1], bh1, c);
#pragma unroll
                for (int reg = 0; reg < 4; reg++)
                    Ts[tt][(quad * 4 + reg) * 40 + half * 16 + m] =
                        f2b_t(gelu_exact(c[reg] + bias));
            }
        }

        s8b A2[2];
#pragma unroll
        for (int tt = 0; tt < 2; tt++)
            A2[tt] = *(const s8b*)&Ts[tt][m * 40 + quad * 8];
#pragma unroll
        for (int nt2 = 0; nt2 < 4; nt2++) {
            const short* p = w2hi + (nt2 * 16 + m) * 256 + kt2 * 32 + quad * 8;
            s8b bh = *(const s8b*)p;
#pragma unroll
            for (int tt = 0; tt < 2; tt++)
                acc2[tt][nt2] = MFMA16(A2[tt], bh, acc2[tt][nt2]);
        }
    }

#pragma unroll
    for (int tt = 0; tt < 2; tt++) {
        if (tt == 1 && !wr1) break;
#pragma unroll
        for (int nt2 = 0; nt2 < 4; nt2++) {
            int col = nt2 * 16 + m;
            float bias = b2b[col];
#pragma unroll
            for (int reg = 0; reg < 4; reg++) {
                int row = rb[tt] + quad * 4 + reg;
                h[(size_t)row * 64 + col] =
                    hnew[tt][nt2][reg] + acc2[tt][nt2][reg] + bias;
            }
        }
    }
}

// ---------------------------------------------------------------------------
// Kernel 6: head — cls pooling, LN, gelu MLP, classifier (fp32 output).
// ---------------------------------------------------------------------------
__global__ void head_kernel(const float* __restrict__ h,
                            const float* __restrict__ ng,
                            const float* __restrict__ nb,
                            const float* __restrict__ w1,
                            const float* __restrict__ b1,
                            const float* __restrict__ w2,
                            const float* __restrict__ b2,
                            float* __restrict__ out) {
    __shared__ float feat[64];
    __shared__ float g1[64];
    int b = blockIdx.x, d = threadIdx.x;

    float s = 0.f;
    for (int e = 0; e < E_N; e++)
        s += h[(size_t)((b * E_N + e) * S_LEN) * 64 + d];
    s *= (1.0f / 25.0f);

    float mu  = waveSum(s) * (1.0f / 64.0f);
    float c   = s - mu;
    float var = waveSum(c * c) * (1.0f / 64.0f);
    feat[d] = c * rsqrtf(var + EPS_F) * ng[d] + nb[d];
    __syncthreads();

    float a = b1[d];
    for (int k = 0; k < 64; k++) a += feat[k] * w1[d * 64 + k];
    g1[d] = gelu_exact(a);
    __syncthreads();

    if (d < NC_N) {
        float a2 = b2[d];
        for (int k = 0; k < 64; k++) a2 += g1[k] * w2[d * 64 + k];
        out[b * NC_N + d] = a2;
    }
}

// ---------------------------------------------------------------------------
extern "C" void kernel_launch(void* const* d_in, const int* in_sizes, int n_in,
                              void* d_out, int out_size, void* d_ws, size_t ws_size,
                              hipStream_t stream) {
    ConvArgs ca;
    for (int i = 0; i < N_IN; i++) ca.src[i] = d_in[i];

    float* F = (float*)d_ws;
    const int offs[N_IN] = {0,360000,360192,360256,360320,360384,360448,409600,
                            410368,426752,427008,427264,427520,427776,428032,
                            493568,494592,560128,560384,560448,560512,564608,
                            564672,568512};
    const float* x       = F + offs[0];
    const float* embed_w = F + offs[1];
    const float* embed_b = F + offs[2];
    const float* eln_g   = F + offs[3];
    const float* eln_b   = F + offs[4];
    const float* cls     = F + offs[5];
    const float* qkv_w   = F + offs[6];
    const float* qkv_b   = F + offs[7];
    const float* out_w   = F + offs[8];
    const float* out_b   = F + offs[9];
    const float* ln1_g   = F + offs[10];
    const float* ln1_b   = F + offs[11];
    const float* ln2_g   = F + offs[12];
    const float* ln2_b   = F + offs[13];
    const float* ff1_w   = F + offs[14];
    const float* ff1_b   = F + offs[15];
    const float* ff2_w   = F + offs[16];
    const float* ff2_b   = F + offs[17];
    const float* norm_g  = F + offs[18];
    const float* norm_b  = F + offs[19];
    const float* h1_w    = F + offs[20];
    const float* h1_b    = F + offs[21];
    const float* h2_w    = F + offs[22];
    const float* h2_b    = F + offs[23];

    float* h   = F + CONV_TOT;                        // [NS_TOT][64] fp32
    u16* qbuf = (u16*)(h + (size_t)NS_TOT * 64);      // [N][H][S][8] bf16
    u16* kbuf = qbuf + (size_t)NS_TOT * 64;
    u16* vbuf = kbuf + (size_t)NS_TOT * 64;
    short* qwhi = (short*)(vbuf + (size_t)NS_TOT * 64);  // 49152 each
    short* qwlo = qwhi + 49152;
    short* w1hi = qwlo + 49152;                          // 65536 each
    short* w1lo = w1hi + 65536;
    short* w2hi = w1lo + 65536;
    short* w2lo = w2hi + 65536;
    short* wohi = w2lo + 65536;                          // 16384 each
    short* wolo = wohi + 16384;

    convert_kernel<<<dim3(N_IN, 8), 256, 0, stream>>>(ca, F);
    split_kernel<<<192, 256, 0, stream>>>(qkv_w, qwhi, qwlo, 49152);
    split_kernel<<<256, 256, 0, stream>>>(ff1_w, w1hi, w1lo, 65536);
    split_kernel<<<256, 256, 0, stream>>>(ff2_w, w2hi, w2lo, 65536);
    split_kernel<<<64, 256, 0, stream>>>(out_w, wohi, wolo, 16384);

    embed_kernel<<<NS_TOT / 4, 256, 0, stream>>>(x, embed_w, embed_b,
                                                 eln_g, eln_b, cls, h);

    for (int l = 0; l < L_N; l++) {
        ln_qkv_mfma<<<(NTILES + 1) / 2, 64, 0, stream>>>(
            h, ln1_g + l * 64, ln1_b + l * 64,
            qwhi + l * 12288, qkv_b + l * 192,
            qbuf, kbuf, vbuf);
        attn_mfma<<<dim3(H_N, N_SEQ), 256, 0, stream>>>(qbuf, kbuf, vbuf);
        out_ff_mfma<<<(NTILES + 1) / 2, 64, 0, stream>>>(
            h, qbuf,
            wohi + l * 4096, out_b + l * 64,
            ln2_g + l * 64, ln2_b + l * 64,
            w1hi + l * 16384, ff1_b + l * 256,
            w2hi + l * 16384, ff2_b + l * 64);
    }

    head_kernel<<<B_N, 64, 0, stream>>>(h, norm_g, norm_b,
                                        h1_w, h1_b, h2_w, h2_b,
                                        (float*)d_out);
}